// Round 8
// baseline (117.784 us; speedup 1.0000x reference)
//
#include <hip/hip_runtime.h>
#include <cstdint>

// ---------------- compile-time DCT index tables + magnitude pool ----------------
// Every DCT coefficient is ±0.25*cos(t*pi/64), t in [0,32], except row 0
// (= sqrt(1/32)). We stage the 34-float pool in GLOBAL memory (k_init) so the
// compiler CANNOT refold it into literals: each FMA reads its coefficient from
// an SGPR (uniform s_load, CSE'd) -> v_fma_f32 acc, ±s[n], v, acc. No 32-bit
// literals, no v_mov materialization, no cross-pass CSE spills.
constexpr double kPI  = 3.14159265358979323846264338327950288;
constexpr double kLN2 = 0.69314718055994530941723212145818;
constexpr double cos_poly(double x) {            // |x| <= pi/2, Taylor
    double x2 = x * x, term = 1.0, sum = 1.0;
    for (int n = 1; n <= 13; ++n) { term *= -x2 / double((2 * n - 1) * (2 * n)); sum += term; }
    return sum;
}
constexpr double cos_idx(int a) {                // cos(a*pi/64), a mod 128
    a &= 127;
    if (a <= 32)  return  cos_poly(a * kPI / 64.0);
    if (a <= 64)  return -cos_poly((64 - a) * kPI / 64.0);
    if (a <= 96)  return -cos_poly((a - 64) * kPI / 64.0);
    return cos_poly((128 - a) * kPI / 64.0);
}
constexpr double csqrt(double v) {
    double x = 1.0;
    for (int i = 0; i < 60; ++i) x = 0.5 * (x + v / x);
    return x;
}
constexpr int aidx(int i, int j) { return ((2 * j + 1) * i) & 127; }
constexpr int tof(int a) { a &= 127; return (a <= 32) ? a : (a <= 64) ? 64 - a : (a <= 96) ? a - 64 : 128 - a; }
constexpr int sof(int a) { a &= 127; return (a <= 32 || a > 96) ? 1 : 0; }   // sign of cos

struct PoolT { float p[34]; };
constexpr PoolT make_pool() {
    PoolT r{};
    for (int t = 0; t <= 32; ++t) r.p[t] = (float)(0.25 * cos_idx(t));  // 0.25 = sqrt(2/32) exactly
    r.p[33] = (float)csqrt(1.0 / 32.0);                                  // row 0 scale
    return r;
}
__device__ constexpr PoolT cPool = make_pool();

// Index/sign tables (fold to immediates after unrolling).
// D32[i][31-k] = (-1)^i D32[i][k]; D32[2m][15-k] = (-1)^m D32[2m][k];
// D32[4m][7-k] = (-1)^m D32[4m][k]  (all exact DCT-II identities).
struct I256 { int t[256]; int s[256]; };         // rows 2m+1 on o[16]
constexpr I256 make_oddI() {
    I256 r{};
    for (int m = 0; m < 16; ++m) for (int k = 0; k < 16; ++k) {
        int a = aidx(2 * m + 1, k); r.t[m*16+k] = tof(a); r.s[m*16+k] = sof(a);
    }
    return r;
}
struct I64 { int t[64]; int s[64]; };            // rows 4m+2 on eo[8]
constexpr I64 make_e2I() {
    I64 r{};
    for (int m = 0; m < 8; ++m) for (int k = 0; k < 8; ++k) {
        int a = aidx(4 * m + 2, k); r.t[m*8+k] = tof(a); r.s[m*8+k] = sof(a);
    }
    return r;
}
struct I16 { int t[16]; int s[16]; };
constexpr I16 make_eeI() {                       // rows 8t on eee[4]; row 0 -> pool[33]
    I16 r{};
    for (int m = 0; m < 4; ++m) for (int k = 0; k < 4; ++k) {
        if (m == 0) { r.t[k] = 33; r.s[k] = 1; }
        else { int a = aidx(8 * m, k); r.t[m*4+k] = tof(a); r.s[m*4+k] = sof(a); }
    }
    return r;
}
constexpr I16 make_eoI() {                       // rows 8t+4 on eeo[4]
    I16 r{};
    for (int m = 0; m < 4; ++m) for (int k = 0; k < 4; ++k) {
        int a = aidx(8 * m + 4, k); r.t[m*4+k] = tof(a); r.s[m*4+k] = sof(a);
    }
    return r;
}
__device__ constexpr I256 iOdd = make_oddI();
__device__ constexpr I64  iE2  = make_e2I();
__device__ constexpr I16  iEE  = make_eeI();
__device__ constexpr I16  iEO  = make_eoI();

struct FTab { float f[64]; };
constexpr FTab make_F() {                        // f(s) = ln2 * sum_g [s in band g] 2^g/n_g
    FTab t{};                                    // (ln2 folded in: we use log2 instead of ln)
    const int lo[6] = {0, 11, 22, 32, 43, 54};
    const int hi[6] = {10, 21, 32, 42, 53, 62};  // s=32 in bands 2 AND 3 (fp64 boundary = 32.0)
    const int n [6] = {66, 187, 306, 286, 165, 45};
    for (int s = 0; s < 64; ++s) {
        double acc = 0.0, w = 1.0;
        for (int g = 0; g < 6; ++g) { if (s >= lo[g] && s <= hi[g]) acc += w / double(n[g]); w *= 2.0; }
        t.f[s] = (float)(acc * kLN2);
    }
    return t;
}
__device__ constexpr FTab cF = make_F();

#define NP  15376   // 16 * 961 patches
#define NPC 46128   // NP * 3 (patch, channel) tasks
#define LPB 961     // 31*31 patches per batch image
#define SST 34      // LDS stride: write bank=(2j+lane) c-free; b64 read bank=2(lane+h),
                    // only lanes l/l+16 alias (2-way = free); 8B-aligned (136|8)

#define CO(T, S, X, A) ((S) ? fmaf(P[T], (X), (A)) : fmaf(-P[T], (X), (A)))

// 32-point DCT-II, 3 butterfly stages, in-place; coefficients from P (SGPRs).
// After folds: o[k]=v[31-k], eo[k]=v[15-k], eee[k]=v[k], eeo[k]=v[7-k].
template <typename EMIT>
__device__ __forceinline__ void dct32(const float* __restrict__ P,
                                      float* __restrict__ v, EMIT&& emit) {
    #pragma unroll
    for (int k = 0; k < 16; ++k) { float a = v[k], b = v[31-k]; v[k] = a + b; v[31-k] = a - b; }
    #pragma unroll
    for (int k = 0; k < 8; ++k)  { float a = v[k], b = v[15-k]; v[k] = a + b; v[15-k] = a - b; }
    #pragma unroll
    for (int k = 0; k < 4; ++k)  { float a = v[k], b = v[7-k];  v[k] = a + b; v[7-k]  = a - b; }
    #pragma unroll
    for (int m = 0; m < 16; m += 2) {            // odd rows 2m+1: 2 chains
        float a = 0.f, b = 0.f;
        #pragma unroll
        for (int k = 0; k < 16; ++k) {
            a = CO(iOdd.t[m*16+k],     iOdd.s[m*16+k],     v[31-k], a);
            b = CO(iOdd.t[(m+1)*16+k], iOdd.s[(m+1)*16+k], v[31-k], b);
        }
        emit(2*m+1, a); emit(2*m+3, b);
    }
    #pragma unroll
    for (int m = 0; m < 8; m += 2) {             // rows 4m+2: 2 chains
        float a = 0.f, b = 0.f;
        #pragma unroll
        for (int k = 0; k < 8; ++k) {
            a = CO(iE2.t[m*8+k],     iE2.s[m*8+k],     v[15-k], a);
            b = CO(iE2.t[(m+1)*8+k], iE2.s[(m+1)*8+k], v[15-k], b);
        }
        emit(4*m+2, a); emit(4*m+6, b);
    }
    {                                            // rows 8t on v[k], 8t+4 on v[7-k]
        float a0=0.f,a1=0.f,a2=0.f,a3=0.f,b0=0.f,b1=0.f,b2=0.f,b3=0.f;
        #pragma unroll
        for (int k = 0; k < 4; ++k) {
            a0 = CO(iEE.t[0*4+k], iEE.s[0*4+k], v[k],   a0);
            a1 = CO(iEE.t[1*4+k], iEE.s[1*4+k], v[k],   a1);
            a2 = CO(iEE.t[2*4+k], iEE.s[2*4+k], v[k],   a2);
            a3 = CO(iEE.t[3*4+k], iEE.s[3*4+k], v[k],   a3);
            b0 = CO(iEO.t[0*4+k], iEO.s[0*4+k], v[7-k], b0);
            b1 = CO(iEO.t[1*4+k], iEO.s[1*4+k], v[7-k], b1);
            b2 = CO(iEO.t[2*4+k], iEO.s[2*4+k], v[7-k], b2);
            b3 = CO(iEO.t[3*4+k], iEO.s[3*4+k], v[7-k], b3);
        }
        emit(0, a0); emit(8, a1); emit(16, a2); emit(24, a3);
        emit(4, b0); emit(12, b1); emit(20, b2); emit(28, b3);
    }
}

// ---------------- kernel 0: stage coefficient pool into global ----------------
// Same work every call (graph-safe); d_ws is re-poisoned before each launch so
// this must run every time anyway.
__global__ __launch_bounds__(64) void k_init(float* __restrict__ pool) {
    const int t = threadIdx.x;
    if (t < 34) pool[t] = cPool.p[t];
}

// ---------------- kernel 1: per-(patch,channel) grade partial ----------------
// One 32-lane group = one (patch, channel); 64-thread single-wave blocks
// (s_barrier lowers to waitcnt-only).  Coefficients via SGPR (pool pointer).
__global__ __launch_bounds__(64, 4) void k_grade(const float* __restrict__ x,
                                                 const float* __restrict__ P,
                                                 float* __restrict__ partial) {
    __shared__ __align__(16) float sS[2][32 * SST];
    __shared__ float sF[64];
    const int tid = threadIdx.x, g = tid >> 5, lane = tid & 31;
    sF[tid] = cF.f[tid];

    const int tc   = blockIdx.x * 2 + g;         // grid exact: 23064*2 = 46128
    const int task = tc / 3, c = tc - task * 3;
    const int b  = task / LPB;
    const int l  = task - b * LPB;
    const int ph = l / 31, pw = l - ph * 31;
    const float4* row = (const float4*)(x + (size_t)(b * 3 + c) * 262144
                                          + (ph * 16 + lane) * 512 + pw * 16);
    float* S = sS[g];
    __syncthreads();                             // single-wave: waitcnt only

    float w[32];                                 // grade weights, hoisted out of the chain
    #pragma unroll
    for (int i = 0; i < 32; ++i) w[i] = sF[lane + i];

    // pass 1: U[r][j] = sum_k P[r][k] D[j][k]; lane = r, contiguous float4 row
    float p[32];
    #pragma unroll
    for (int q = 0; q < 8; ++q) {
        float4 f = row[q];
        p[4*q] = f.x; p[4*q+1] = f.y; p[4*q+2] = f.z; p[4*q+3] = f.w;
    }
    dct32(P, p, [&](int j, float acc) { S[j * SST + lane] = acc; });
    __syncthreads();

    // pass 2: lane = column of U; transposed read as 16 x ds_read_b64
    float u[32];
    #pragma unroll
    for (int h = 0; h < 16; ++h) {
        float2 uu = *(const float2*)&S[lane * SST + 2 * h];
        u[2*h] = uu.x; u[2*h+1] = uu.y;
    }
    float gsum = 0.0f;
    dct32(P, u, [&](int i, float z) {
        gsum = fmaf(__log2f(fabsf(z) + 1.0f), w[i], gsum);   // ln2 folded into w
    });
    #pragma unroll
    for (int off = 16; off > 0; off >>= 1) gsum += __shfl_down(gsum, off, 32);
    if (lane == 0) partial[tc] = gsum;
}

// ---------------- kernel 2: fused select + gather ----------------
// Block b: sum 3 channel partials (deterministic order), top-2/bottom-2 via
// u64 key = grade_bits<<32 | idx (matches stable-argsort tie semantics), then
// copy the 4 selected raw patches (level_y == patches: LEVEL_FILT all-ones,
// D orthonormal).
__global__ __launch_bounds__(256) void k_selgather(const float* __restrict__ partial,
                                                   const float* __restrict__ x,
                                                   float* __restrict__ out) {
    __shared__ unsigned long long smx1[256], smx2[256], smn1[256], smn2[256];
    __shared__ int ssel[4];
    const int b = blockIdx.x, tid = threadIdx.x;
    unsigned long long mx1 = 0, mx2 = 0, mn1 = ~0ULL, mn2 = ~0ULL;
    for (int l = tid; l < LPB; l += 256) {
        const float* pp = partial + (size_t)(b * LPB + l) * 3;
        float gr = pp[0] + pp[1] + pp[2];
        unsigned int bits = __float_as_uint(gr);
        unsigned long long k = ((unsigned long long)bits << 32) | (unsigned int)l;
        if (k > mx1) { mx2 = mx1; mx1 = k; } else if (k > mx2) { mx2 = k; }
        if (k < mn1) { mn2 = mn1; mn1 = k; } else if (k < mn2) { mn2 = k; }
    }
    smx1[tid] = mx1; smx2[tid] = mx2; smn1[tid] = mn1; smn2[tid] = mn2;
    for (int off = 128; off > 0; off >>= 1) {
        __syncthreads();
        if (tid < off) {
            unsigned long long a1 = smx1[tid], a2 = smx2[tid], b1 = smx1[tid + off], b2 = smx2[tid + off];
            unsigned long long lo = a1 < b1 ? a1 : b1, hi = a1 < b1 ? b1 : a1;
            unsigned long long c2 = a2 > b2 ? a2 : b2;
            smx1[tid] = hi; smx2[tid] = lo > c2 ? lo : c2;
            a1 = smn1[tid]; a2 = smn2[tid]; b1 = smn1[tid + off]; b2 = smn2[tid + off];
            lo = a1 < b1 ? a1 : b1; hi = a1 < b1 ? b1 : a1;
            c2 = a2 < b2 ? a2 : b2;
            smn1[tid] = lo; smn2[tid] = hi < c2 ? hi : c2;
        }
    }
    __syncthreads();
    if (tid == 0) {
        ssel[0] = (int)(smn1[0] & 0xffffffffu);  // x_minmin
        ssel[1] = (int)(smx1[0] & 0xffffffffu);  // x_maxmax
        ssel[2] = (int)(smn2[0] & 0xffffffffu);  // x_minmin1
        ssel[3] = (int)(smx2[0] & 0xffffffffu);  // x_maxmax1
    }
    __syncthreads();

    // gather: 4 outputs x 3 ch x 32 x 32 floats = 3072 float4 per batch
    #pragma unroll
    for (int it = 0; it < 12; ++it) {
        const int q  = it * 256 + tid;           // [0, 3072)
        const int o  = q / 768;
        const int r2 = q - o * 768;
        const int c  = r2 >> 8;
        const int p  = r2 & 255;
        const int i  = p >> 3, j4 = p & 7;
        const int l  = ssel[o];
        const int r0 = (l / 31) * 16, c0 = (l - (l / 31) * 31) * 16;
        const float4 v = *(const float4*)(x + ((size_t)(b * 3 + c) * 512 + r0 + i) * 512 + c0 + 4 * j4);
        *(float4*)(out + (size_t)o * 49152 + b * 3072 + c * 1024 + i * 32 + 4 * j4) = v;
    }
}

extern "C" void kernel_launch(void* const* d_in, const int* in_sizes, int n_in,
                              void* d_out, int out_size, void* d_ws, size_t ws_size,
                              hipStream_t stream) {
    const float* x = (const float*)d_in[0];
    float* out     = (float*)d_out;
    float* partial = (float*)d_ws;               // NPC floats (184 KB)
    float* pool    = (float*)d_ws + 47104;       // 34 floats, past partial
    k_init     <<<1,       64, 0, stream>>>(pool);
    k_grade    <<<NPC / 2, 64, 0, stream>>>(x, pool, partial);
    k_selgather<<<16,     256, 0, stream>>>(partial, x, out);
}

// Round 9
// 106.178 us; speedup vs baseline: 1.1093x; 1.1093x over previous
//
#include <hip/hip_runtime.h>
#include <cstdint>

typedef _Float16 f16x8 __attribute__((ext_vector_type(8)));
typedef float    f32x4 __attribute__((ext_vector_type(4)));

// ---------------- compile-time DCT matrix + grade filter ----------------
constexpr double kPI  = 3.14159265358979323846264338327950288;
constexpr double kLN2 = 0.69314718055994530941723212145818;
constexpr double cos_poly(double x) {            // |x| <= pi/2, Taylor
    double x2 = x * x, term = 1.0, sum = 1.0;
    for (int n = 1; n <= 13; ++n) { term *= -x2 / double((2 * n - 1) * (2 * n)); sum += term; }
    return sum;
}
constexpr double cos_idx(int a) {                // cos(a*pi/64), a mod 128
    a &= 127;
    if (a <= 32)  return  cos_poly(a * kPI / 64.0);
    if (a <= 64)  return -cos_poly((64 - a) * kPI / 64.0);
    if (a <= 96)  return -cos_poly((a - 64) * kPI / 64.0);
    return cos_poly((128 - a) * kPI / 64.0);
}
constexpr double csqrt(double v) {
    double x = 1.0;
    for (int i = 0; i < 60; ++i) x = 0.5 * (x + v / x);
    return x;
}
struct DTab { float d[1024]; };
constexpr DTab make_D() {
    DTab t{};
    const double s0 = csqrt(1.0 / 32.0);
    for (int i = 0; i < 32; ++i) {
        double sc = (i == 0) ? s0 : 0.25;        // sqrt(2/32) == 0.25 exactly
        for (int j = 0; j < 32; ++j)
            t.d[i * 32 + j] = (float)(sc * cos_idx(((2 * j + 1) * i) & 127));
    }
    return t;
}
struct FTab { float f[64]; };
constexpr FTab make_F() {                        // f(s) = ln2 * sum_g [s in band g] 2^g/n_g
    FTab t{};                                    // ln2 folded in: kernel uses log2
    const int lo[6] = {0, 11, 22, 32, 43, 54};
    const int hi[6] = {10, 21, 32, 42, 53, 62};  // s=32 in bands 2 AND 3 (fp64 boundary = 32.0)
    const int n [6] = {66, 187, 306, 286, 165, 45};
    for (int s = 0; s < 64; ++s) {
        double acc = 0.0, w = 1.0;
        for (int g = 0; g < 6; ++g) { if (s >= lo[g] && s <= hi[g]) acc += w / double(n[g]); w *= 2.0; }
        t.f[s] = (float)(acc * kLN2);
    }
    return t;
}
__device__ constexpr DTab cD = make_D();
__device__ constexpr FTab cF = make_F();

#define NP  15376   // 16 * 961 patches
#define NPC 46128   // NP * 3 (patch, channel) tasks
#define LPB 961     // 31*31 patches per batch image
#define TP  36      // LDS T stride: writes bank (16q+4r+n)%32 = 2-way (free);
                    // b128 reads 16B-aligned, uniform 8-per-bank

// ---------------- kernel 0: stage D fragments (fp16, MFMA lane order) -------
// Frag[tile][lane][j] = D[16*tile + (lane&15)][(lane>>4)*8 + j].
// This is BOTH the A-fragment of D (stage 1) and the B-fragment of D^T
// (stage 2): B[k][n] = (D^T)[k][n] = D[n][k] -> same index formula.
__global__ __launch_bounds__(128) void k_init(_Float16* __restrict__ dfrag) {
    const int t = threadIdx.x;                   // 128 = 2 tiles x 64 lanes
    const int tile = t >> 6, lane = t & 63;
    const int m  = 16 * tile + (lane & 15);
    const int k0 = ((lane >> 4) & 3) * 8;
    #pragma unroll
    for (int j = 0; j < 8; ++j)
        dfrag[t * 8 + j] = (_Float16)cD.d[m * 32 + k0 + j];
}

// ---------------- kernel 1: per-(patch,channel) grade via MFMA ----------------
// One wave = one task.  Z = D*P*D^T with mfma_f32_16x16x32_f16 (fp16-hi:
// grade err ~9e-3 << inter-patch gaps ~0.1-0.6).  Layouts:
//   A[m=lane&15][k=quad*8+j]   (verified m120)
//   B[k=quad*8+j][n=lane&15]   (duality / m92 loader)
//   C/D: col=lane&15, row=quad*4+reg  (verified m89)
__global__ __launch_bounds__(128, 4) void k_grade(const float* __restrict__ x,
                                                  const _Float16* __restrict__ dfrag,
                                                  float* __restrict__ partial) {
    __shared__ __align__(16) float sT[2][32 * TP];
    __shared__ float sF[64];
    const int tid  = threadIdx.x;
    const int wv   = tid >> 6, lane = tid & 63;
    const int quad = lane >> 4, n = lane & 15;
    if (tid < 64) sF[tid] = cF.f[tid];

    const int tc   = blockIdx.x * 2 + wv;        // grid exact: 23064*2 = 46128
    const int task = tc / 3, c = tc - task * 3;
    const int b  = task / LPB, l = task - b * LPB;
    const int ph = l / 31, pw = l - ph * 31;

    // D fragments, resident in 8 VGPRs (L2-hot: same 2 KB for all waves)
    const f16x8* DF = (const f16x8*)dfrag;
    const f16x8 d0 = DF[lane], d1 = DF[64 + lane];

    // load P directly in B-operand layout: element P[quad*8+j][n (+16)]
    const float* pp = x + (size_t)(b * 3 + c) * 262144
                        + (size_t)(ph * 16 + quad * 8) * 512 + pw * 16 + n;
    f16x8 p0, p1;
    #pragma unroll
    for (int j = 0; j < 8; ++j) {
        p0[j] = (_Float16)pp[j * 512];
        p1[j] = (_Float16)pp[j * 512 + 16];
    }

    // stage 1: T = D * P (4 tiles of 16x16, K=32 in one MFMA each)
    const f32x4 z4 = {0.f, 0.f, 0.f, 0.f};
    f32x4 t00 = __builtin_amdgcn_mfma_f32_16x16x32_f16(d0, p0, z4, 0, 0, 0);
    f32x4 t01 = __builtin_amdgcn_mfma_f32_16x16x32_f16(d0, p1, z4, 0, 0, 0);
    f32x4 t10 = __builtin_amdgcn_mfma_f32_16x16x32_f16(d1, p0, z4, 0, 0, 0);
    f32x4 t11 = __builtin_amdgcn_mfma_f32_16x16x32_f16(d1, p1, z4, 0, 0, 0);

    // C-layout -> LDS [row][col] (pad 36)
    float* S = sT[wv];
    #pragma unroll
    for (int r = 0; r < 4; ++r) {
        S[(quad * 4 + r) * TP + n]           = t00[r];
        S[(quad * 4 + r) * TP + 16 + n]      = t01[r];
        S[(16 + quad * 4 + r) * TP + n]      = t10[r];
        S[(16 + quad * 4 + r) * TP + 16 + n] = t11[r];
    }
    __syncthreads();

    // read T in A-operand layout (m = n + 16*mt, k = quad*8+j), convert fp16
    f16x8 a0, a1;
    {
        const float* rp = &S[n * TP + quad * 8];
        const float4 x0 = *(const float4*)(rp);
        const float4 x1 = *(const float4*)(rp + 4);
        const float4 x2 = *(const float4*)(rp + 16 * TP);
        const float4 x3 = *(const float4*)(rp + 16 * TP + 4);
        a0[0]=(_Float16)x0.x; a0[1]=(_Float16)x0.y; a0[2]=(_Float16)x0.z; a0[3]=(_Float16)x0.w;
        a0[4]=(_Float16)x1.x; a0[5]=(_Float16)x1.y; a0[6]=(_Float16)x1.z; a0[7]=(_Float16)x1.w;
        a1[0]=(_Float16)x2.x; a1[1]=(_Float16)x2.y; a1[2]=(_Float16)x2.z; a1[3]=(_Float16)x2.w;
        a1[4]=(_Float16)x3.x; a1[5]=(_Float16)x3.y; a1[6]=(_Float16)x3.z; a1[7]=(_Float16)x3.w;
    }

    // stage 2: Z = T * D^T (B-frag of D^T == D fragments)
    f32x4 q00 = __builtin_amdgcn_mfma_f32_16x16x32_f16(a0, d0, z4, 0, 0, 0);
    f32x4 q01 = __builtin_amdgcn_mfma_f32_16x16x32_f16(a0, d1, z4, 0, 0, 0);
    f32x4 q10 = __builtin_amdgcn_mfma_f32_16x16x32_f16(a1, d0, z4, 0, 0, 0);
    f32x4 q11 = __builtin_amdgcn_mfma_f32_16x16x32_f16(a1, d1, z4, 0, 0, 0);

    // grade: s = row+col = 16*(mt+nt) + (4*quad + n) + r ; preload 12 weights
    const int sb = quad * 4 + n;
    float W[12];
    #pragma unroll
    for (int t2 = 0; t2 < 3; ++t2)
        #pragma unroll
        for (int r = 0; r < 4; ++r) W[t2 * 4 + r] = sF[sb + 16 * t2 + r];

    float gsum = 0.f;
    #pragma unroll
    for (int r = 0; r < 4; ++r) {
        gsum = fmaf(__log2f(fabsf(q00[r]) + 1.f), W[r],     gsum);
        gsum = fmaf(__log2f(fabsf(q01[r]) + 1.f), W[4 + r], gsum);
        gsum = fmaf(__log2f(fabsf(q10[r]) + 1.f), W[4 + r], gsum);
        gsum = fmaf(__log2f(fabsf(q11[r]) + 1.f), W[8 + r], gsum);
    }
    #pragma unroll
    for (int off = 32; off > 0; off >>= 1) gsum += __shfl_down(gsum, off, 64);
    if (lane == 0) partial[tc] = gsum;
}

// ---------------- kernel 2: fused select + gather ----------------
// Block b: sum 3 channel partials (deterministic order), top-2/bottom-2 via
// u64 key = grade_bits<<32 | idx (matches stable-argsort tie semantics), then
// copy the 4 selected raw patches (level_y == patches: LEVEL_FILT all-ones,
// D orthonormal).
__global__ __launch_bounds__(256) void k_selgather(const float* __restrict__ partial,
                                                   const float* __restrict__ x,
                                                   float* __restrict__ out) {
    __shared__ unsigned long long smx1[256], smx2[256], smn1[256], smn2[256];
    __shared__ int ssel[4];
    const int b = blockIdx.x, tid = threadIdx.x;
    unsigned long long mx1 = 0, mx2 = 0, mn1 = ~0ULL, mn2 = ~0ULL;
    for (int l = tid; l < LPB; l += 256) {
        const float* pp = partial + (size_t)(b * LPB + l) * 3;
        float gr = pp[0] + pp[1] + pp[2];
        unsigned int bits = __float_as_uint(gr);
        unsigned long long k = ((unsigned long long)bits << 32) | (unsigned int)l;
        if (k > mx1) { mx2 = mx1; mx1 = k; } else if (k > mx2) { mx2 = k; }
        if (k < mn1) { mn2 = mn1; mn1 = k; } else if (k < mn2) { mn2 = k; }
    }
    smx1[tid] = mx1; smx2[tid] = mx2; smn1[tid] = mn1; smn2[tid] = mn2;
    for (int off = 128; off > 0; off >>= 1) {
        __syncthreads();
        if (tid < off) {
            unsigned long long a1 = smx1[tid], a2 = smx2[tid], b1 = smx1[tid + off], b2 = smx2[tid + off];
            unsigned long long lo = a1 < b1 ? a1 : b1, hi = a1 < b1 ? b1 : a1;
            unsigned long long c2 = a2 > b2 ? a2 : b2;
            smx1[tid] = hi; smx2[tid] = lo > c2 ? lo : c2;
            a1 = smn1[tid]; a2 = smn2[tid]; b1 = smn1[tid + off]; b2 = smn2[tid + off];
            lo = a1 < b1 ? a1 : b1; hi = a1 < b1 ? b1 : a1;
            c2 = a2 < b2 ? a2 : b2;
            smn1[tid] = lo; smn2[tid] = hi < c2 ? hi : c2;
        }
    }
    __syncthreads();
    if (tid == 0) {
        ssel[0] = (int)(smn1[0] & 0xffffffffu);  // x_minmin
        ssel[1] = (int)(smx1[0] & 0xffffffffu);  // x_maxmax
        ssel[2] = (int)(smn2[0] & 0xffffffffu);  // x_minmin1
        ssel[3] = (int)(smx2[0] & 0xffffffffu);  // x_maxmax1
    }
    __syncthreads();

    // gather: 4 outputs x 3 ch x 32 x 32 floats = 3072 float4 per batch
    #pragma unroll
    for (int it = 0; it < 12; ++it) {
        const int q  = it * 256 + tid;           // [0, 3072)
        const int o  = q / 768;
        const int r2 = q - o * 768;
        const int c  = r2 >> 8;
        const int p  = r2 & 255;
        const int i  = p >> 3, j4 = p & 7;
        const int l  = ssel[o];
        const int r0 = (l / 31) * 16, c0 = (l - (l / 31) * 31) * 16;
        const float4 v = *(const float4*)(x + ((size_t)(b * 3 + c) * 512 + r0 + i) * 512 + c0 + 4 * j4);
        *(float4*)(out + (size_t)o * 49152 + b * 3072 + c * 1024 + i * 32 + 4 * j4) = v;
    }
}

extern "C" void kernel_launch(void* const* d_in, const int* in_sizes, int n_in,
                              void* d_out, int out_size, void* d_ws, size_t ws_size,
                              hipStream_t stream) {
    const float* x = (const float*)d_in[0];
    float* out     = (float*)d_out;
    float* partial = (float*)d_ws;                     // NPC floats
    _Float16* dfrag = (_Float16*)((char*)d_ws + 47104 * 4);  // 1024 halfs, 16B-aligned
    k_init     <<<1,       128, 0, stream>>>(dfrag);
    k_grade    <<<NPC / 2, 128, 0, stream>>>(x, dfrag, partial);
    k_selgather<<<16,      256, 0, stream>>>(partial, x, out);
}